// Round 1
// baseline (913.349 us; speedup 1.0000x reference)
//
#include <hip/hip_runtime.h>
#include <hip/hip_bf16.h>

// Problem constants (from setup_inputs)
#define BB 8
#define NN 16384
#define MM 4096
#define C1 64
#define C2 256
#define CIN1 320          // C1 + C2
#define CO 256
#define MTOT (BB * NN)    // 131072

// Workspace layout (bytes)
#define STATS_OFF 0                // 8 * 256 floats = 8192 B
#define FLAG_OFF  8192
#define F2T_OFF   65536                       // bf16 [B, M, C2]  = 16,777,216 B
#define XT_OFF    (65536 + 16777216)          // bf16 [MTOT, 320] = 83,886,080 B
#define H2_OFF    (65536 + 16777216 + 83886080) // bf16 [B, CO, N] = 67,108,864 B

__device__ __forceinline__ float bf2f(unsigned short u) {
    unsigned v = ((unsigned)u) << 16;
    float f;
    __builtin_memcpy(&f, &v, 4);
    return f;
}
__device__ __forceinline__ unsigned short f2bf(float f) {
    unsigned u;
    __builtin_memcpy(&u, &f, 4);
    unsigned r = u + 0x7fffu + ((u >> 16) & 1u);  // RNE
    return (unsigned short)(r >> 16);
}

// ---------------- init: zero stats, detect idx element width ----------------
__global__ void k_init(const void* idx_raw, int* flag64, float* stats) {
    int t = threadIdx.x;
    for (int i = t; i < 8 * 256; i += 256) stats[i] = 0.f;
    if (t == 0) {
        const int* a = (const int*)idx_raw;
        int all0 = 1;
        for (int j = 1; j < 64; j += 2) all0 &= (a[j] == 0);
        *flag64 = all0;  // 1 => idx stored as int64
    }
}

// ---------------- tiled transpose f2 [B,C2,M] -> f2t bf16 [B,M,C2] ----------
__global__ void k_tr_f2(const float* __restrict__ f2, unsigned short* __restrict__ f2t) {
    __shared__ float tile[32][33];
    int b = blockIdx.z;
    int c0 = blockIdx.y * 32;
    int m0 = blockIdx.x * 32;
    int tx = threadIdx.x, ty = threadIdx.y;  // 32 x 8
    const float* src = f2 + ((size_t)b * C2 + c0) * MM + m0;
#pragma unroll
    for (int j = 0; j < 4; ++j)
        tile[ty + 8 * j][tx] = src[(size_t)(ty + 8 * j) * MM + tx];
    __syncthreads();
    unsigned short* dst = f2t + ((size_t)b * MM + m0) * C2 + c0;
#pragma unroll
    for (int j = 0; j < 4; ++j)
        dst[(size_t)(ty + 8 * j) * C2 + tx] = f2bf(tile[tx][ty + 8 * j]);
}

// ---------------- tiled transpose f1 [B,C1,N] -> xT[:,0:64] bf16 ------------
__global__ void k_tr_f1(const float* __restrict__ f1, unsigned short* __restrict__ xT) {
    __shared__ float tile[32][33];
    int b = blockIdx.z;
    int c0 = blockIdx.y * 32;
    int n0 = blockIdx.x * 32;
    int tx = threadIdx.x, ty = threadIdx.y;
    const float* src = f1 + ((size_t)b * C1 + c0) * NN + n0;
#pragma unroll
    for (int j = 0; j < 4; ++j)
        tile[ty + 8 * j][tx] = src[(size_t)(ty + 8 * j) * NN + tx];
    __syncthreads();
    unsigned short* dst = xT + ((size_t)b * NN + n0) * CIN1 + c0;
#pragma unroll
    for (int j = 0; j < 4; ++j)
        dst[(size_t)(ty + 8 * j) * CIN1 + tx] = f2bf(tile[tx][ty + 8 * j]);
}

// ---------------- 3-NN inverse-distance interpolation -> xT[:,64:320] -------
__global__ void k_interp(const float* __restrict__ p1, const float* __restrict__ p2,
                         const void* __restrict__ idxv, const int* __restrict__ flag64,
                         const unsigned short* __restrict__ f2t,
                         unsigned short* __restrict__ xT) {
    int t = threadIdx.x;
    int p = t >> 5, lane = t & 31;
    size_t pt = (size_t)blockIdx.x * 8 + p;   // global point id in [0, MTOT)
    int b = (int)(pt >> 14);
    int m0, m1, m2;
    if (*flag64) {
        const long long* id = (const long long*)idxv;
        m0 = (int)id[pt * 3 + 0];
        m1 = (int)id[pt * 3 + 1];
        m2 = (int)id[pt * 3 + 2];
    } else {
        const int* id = (const int*)idxv;
        m0 = id[pt * 3 + 0];
        m1 = id[pt * 3 + 1];
        m2 = id[pt * 3 + 2];
    }
    float qx = p1[pt * 3 + 0], qy = p1[pt * 3 + 1], qz = p1[pt * 3 + 2];
    const float* pb = p2 + (size_t)b * MM * 3;
    float dx, dy, dz;
    dx = qx - pb[m0 * 3 + 0]; dy = qy - pb[m0 * 3 + 1]; dz = qz - pb[m0 * 3 + 2];
    float d0 = dx * dx + dy * dy + dz * dz;
    dx = qx - pb[m1 * 3 + 0]; dy = qy - pb[m1 * 3 + 1]; dz = qz - pb[m1 * 3 + 2];
    float d1 = dx * dx + dy * dy + dz * dz;
    dx = qx - pb[m2 * 3 + 0]; dy = qy - pb[m2 * 3 + 1]; dz = qz - pb[m2 * 3 + 2];
    float d2v = dx * dx + dy * dy + dz * dz;
    float r0 = 1.f / (d0 + 1e-8f), r1 = 1.f / (d1 + 1e-8f), r2 = 1.f / (d2v + 1e-8f);
    float inv = 1.f / (r0 + r1 + r2);
    float w0 = r0 * inv, w1 = r1 * inv, w2 = r2 * inv;

    const unsigned short* fb = f2t + (size_t)b * MM * C2;
    int c0 = lane * 8;
    uint4 va = *(const uint4*)(fb + (size_t)m0 * C2 + c0);
    uint4 vb = *(const uint4*)(fb + (size_t)m1 * C2 + c0);
    uint4 vc = *(const uint4*)(fb + (size_t)m2 * C2 + c0);

    float r[8];
    {
        const unsigned av[4] = {va.x, va.y, va.z, va.w};
        const unsigned bv[4] = {vb.x, vb.y, vb.z, vb.w};
        const unsigned cv[4] = {vc.x, vc.y, vc.z, vc.w};
#pragma unroll
        for (int q = 0; q < 4; ++q) {
            float alo = bf2f((unsigned short)(av[q] & 0xffff));
            float ahi = bf2f((unsigned short)(av[q] >> 16));
            float blo = bf2f((unsigned short)(bv[q] & 0xffff));
            float bhi = bf2f((unsigned short)(bv[q] >> 16));
            float clo = bf2f((unsigned short)(cv[q] & 0xffff));
            float chi = bf2f((unsigned short)(cv[q] >> 16));
            r[2 * q + 0] = w0 * alo + w1 * blo + w2 * clo;
            r[2 * q + 1] = w0 * ahi + w1 * bhi + w2 * chi;
        }
    }
    uint4 outv;
    outv.x = (unsigned)f2bf(r[0]) | ((unsigned)f2bf(r[1]) << 16);
    outv.y = (unsigned)f2bf(r[2]) | ((unsigned)f2bf(r[3]) << 16);
    outv.z = (unsigned)f2bf(r[4]) | ((unsigned)f2bf(r[5]) << 16);
    outv.w = (unsigned)f2bf(r[6]) | ((unsigned)f2bf(r[7]) << 16);
    *(uint4*)(xT + pt * CIN1 + C1 + c0) = outv;
}

// ---------------- GEMM1: h1[row,o] = sum_i xT[row,i] * W1[o,i]  + stats ----
#define Bb_M 64
#define Bb_N 64
#define Bb_K 16
__launch_bounds__(256)
__global__ void k_gemm1(const unsigned short* __restrict__ xT,
                        const float* __restrict__ W1, float* __restrict__ h1,
                        float* __restrict__ sum1, float* __restrict__ ssq1) {
    __shared__ float As[Bb_K][Bb_M + 4];
    __shared__ float Bs[Bb_K][Bb_N + 4];
    __shared__ float s_sum[Bb_N], s_ssq[Bb_N];
    int t = threadIdx.x;
    int tx = t & 15, ty = t >> 4;
    long rbase = (long)blockIdx.x * Bb_M;
    int cb = blockIdx.y * Bb_N;
    float acc[4][4] = {};

    int arow = t >> 2;
    int ak = (t & 3) * 4;
    const unsigned short* Aptr = xT + (size_t)(rbase + arow) * CIN1 + ak;
    int bk = t & 15;
    int bc = t >> 4;

    for (int k0 = 0; k0 < CIN1; k0 += Bb_K) {
        ushort4 av = *(const ushort4*)(Aptr + k0);
        As[ak + 0][arow] = bf2f(av.x);
        As[ak + 1][arow] = bf2f(av.y);
        As[ak + 2][arow] = bf2f(av.z);
        As[ak + 3][arow] = bf2f(av.w);
#pragma unroll
        for (int j = 0; j < 4; ++j) {
            int c = bc + 16 * j;
            Bs[bk][c] = W1[(size_t)(cb + c) * CIN1 + k0 + bk];
        }
        __syncthreads();
#pragma unroll
        for (int kk = 0; kk < Bb_K; ++kk) {
            float4 a4 = *(const float4*)&As[kk][4 * tx];
            float4 b4 = *(const float4*)&Bs[kk][4 * ty];
            acc[0][0] += a4.x * b4.x; acc[0][1] += a4.x * b4.y; acc[0][2] += a4.x * b4.z; acc[0][3] += a4.x * b4.w;
            acc[1][0] += a4.y * b4.x; acc[1][1] += a4.y * b4.y; acc[1][2] += a4.y * b4.z; acc[1][3] += a4.y * b4.w;
            acc[2][0] += a4.z * b4.x; acc[2][1] += a4.z * b4.y; acc[2][2] += a4.z * b4.z; acc[2][3] += a4.z * b4.w;
            acc[3][0] += a4.w * b4.x; acc[3][1] += a4.w * b4.y; acc[3][2] += a4.w * b4.z; acc[3][3] += a4.w * b4.w;
        }
        __syncthreads();
    }

    if (t < Bb_N) { s_sum[t] = 0.f; s_ssq[t] = 0.f; }
    __syncthreads();
    long r0 = rbase + 4 * tx;
#pragma unroll
    for (int i = 0; i < 4; ++i) {
        float4 v = make_float4(acc[i][0], acc[i][1], acc[i][2], acc[i][3]);
        *(float4*)&h1[(size_t)(r0 + i) * CO + cb + 4 * ty] = v;
    }
#pragma unroll
    for (int j = 0; j < 4; ++j) {
        float s = acc[0][j] + acc[1][j] + acc[2][j] + acc[3][j];
        float q = acc[0][j] * acc[0][j] + acc[1][j] * acc[1][j] + acc[2][j] * acc[2][j] + acc[3][j] * acc[3][j];
        atomicAdd(&s_sum[4 * ty + j], s);
        atomicAdd(&s_ssq[4 * ty + j], q);
    }
    __syncthreads();
    if (t < Bb_N) {
        atomicAdd(&sum1[cb + t], s_sum[t]);
        atomicAdd(&ssq1[cb + t], s_ssq[t]);
    }
}

// ---------------- BN finalize: scale/shift per channel ----------------------
__global__ void k_bnfin(const float* __restrict__ sum, const float* __restrict__ ssq,
                        const float* __restrict__ g, const float* __restrict__ bb,
                        float* __restrict__ scale, float* __restrict__ shift) {
    int c = threadIdx.x;
    const float invn = 1.f / (float)MTOT;
    float m = sum[c] * invn;
    float v = ssq[c] * invn - m * m;
    float s = g[c] * rsqrtf(v + 1e-5f);
    scale[c] = s;
    shift[c] = bb[c] - m * s;
}

// ---------------- GEMM2: BN1+ReLU applied to h1 at staging ------------------
__launch_bounds__(256)
__global__ void k_gemm2(const float* __restrict__ h1, const float* __restrict__ W2,
                        const float* __restrict__ scale1, const float* __restrict__ shift1,
                        unsigned short* __restrict__ h2,
                        float* __restrict__ sum2, float* __restrict__ ssq2) {
    __shared__ float As[Bb_K][Bb_M + 4];
    __shared__ float Bs[Bb_K][Bb_N + 4];
    __shared__ float s_sum[Bb_N], s_ssq[Bb_N];
    __shared__ float sc[CO], sh[CO];
    int t = threadIdx.x;
    int tx = t & 15, ty = t >> 4;
    long rbase = (long)blockIdx.x * Bb_M;
    int cb = blockIdx.y * Bb_N;
    float acc[4][4] = {};

    sc[t] = scale1[t];
    sh[t] = shift1[t];
    __syncthreads();

    int arow = t >> 2;
    int ak = (t & 3) * 4;
    const float* Aptr = h1 + (size_t)(rbase + arow) * CO + ak;
    int bk = t & 15;
    int bc = t >> 4;

    for (int k0 = 0; k0 < CO; k0 += Bb_K) {
        float4 av = *(const float4*)(Aptr + k0);
        As[ak + 0][arow] = fmaxf(av.x * sc[k0 + ak + 0] + sh[k0 + ak + 0], 0.f);
        As[ak + 1][arow] = fmaxf(av.y * sc[k0 + ak + 1] + sh[k0 + ak + 1], 0.f);
        As[ak + 2][arow] = fmaxf(av.z * sc[k0 + ak + 2] + sh[k0 + ak + 2], 0.f);
        As[ak + 3][arow] = fmaxf(av.w * sc[k0 + ak + 3] + sh[k0 + ak + 3], 0.f);
#pragma unroll
        for (int j = 0; j < 4; ++j) {
            int c = bc + 16 * j;
            Bs[bk][c] = W2[(size_t)(cb + c) * CO + k0 + bk];
        }
        __syncthreads();
#pragma unroll
        for (int kk = 0; kk < Bb_K; ++kk) {
            float4 a4 = *(const float4*)&As[kk][4 * tx];
            float4 b4 = *(const float4*)&Bs[kk][4 * ty];
            acc[0][0] += a4.x * b4.x; acc[0][1] += a4.x * b4.y; acc[0][2] += a4.x * b4.z; acc[0][3] += a4.x * b4.w;
            acc[1][0] += a4.y * b4.x; acc[1][1] += a4.y * b4.y; acc[1][2] += a4.y * b4.z; acc[1][3] += a4.y * b4.w;
            acc[2][0] += a4.z * b4.x; acc[2][1] += a4.z * b4.y; acc[2][2] += a4.z * b4.z; acc[2][3] += a4.z * b4.w;
            acc[3][0] += a4.w * b4.x; acc[3][1] += a4.w * b4.y; acc[3][2] += a4.w * b4.z; acc[3][3] += a4.w * b4.w;
        }
        __syncthreads();
    }

    if (t < Bb_N) { s_sum[t] = 0.f; s_ssq[t] = 0.f; }
    __syncthreads();
    long r0 = rbase + 4 * tx;         // 4 consecutive rows (same b, consecutive n)
    int bq = (int)(r0 >> 14);
    int n0 = (int)(r0 & (NN - 1));
#pragma unroll
    for (int j = 0; j < 4; ++j) {
        int o = cb + 4 * ty + j;
        ushort4 hv;
        hv.x = f2bf(acc[0][j]); hv.y = f2bf(acc[1][j]);
        hv.z = f2bf(acc[2][j]); hv.w = f2bf(acc[3][j]);
        *(ushort4*)(h2 + (((size_t)(bq * CO + o)) << 14) + n0) = hv;
        float s = acc[0][j] + acc[1][j] + acc[2][j] + acc[3][j];
        float q = acc[0][j] * acc[0][j] + acc[1][j] * acc[1][j] + acc[2][j] * acc[2][j] + acc[3][j] * acc[3][j];
        atomicAdd(&s_sum[4 * ty + j], s);
        atomicAdd(&s_ssq[4 * ty + j], q);
    }
    __syncthreads();
    if (t < Bb_N) {
        atomicAdd(&sum2[cb + t], s_sum[t]);
        atomicAdd(&ssq2[cb + t], s_ssq[t]);
    }
}

// ---------------- final elementwise BN2+ReLU -> fp32 out --------------------
__global__ void k_apply(const unsigned short* __restrict__ h2,
                        const float* __restrict__ scale2, const float* __restrict__ shift2,
                        float* __restrict__ out) {
    size_t i = ((size_t)blockIdx.x * 256 + threadIdx.x) * 4;
    int o = (int)((i >> 14) & 255);
    float s = scale2[o], d = shift2[o];
    ushort4 hv = *(const ushort4*)(h2 + i);
    float4 v;
    v.x = fmaxf(bf2f(hv.x) * s + d, 0.f);
    v.y = fmaxf(bf2f(hv.y) * s + d, 0.f);
    v.z = fmaxf(bf2f(hv.z) * s + d, 0.f);
    v.w = fmaxf(bf2f(hv.w) * s + d, 0.f);
    *(float4*)&out[i] = v;
}

extern "C" void kernel_launch(void* const* d_in, const int* in_sizes, int n_in,
                              void* d_out, int out_size, void* d_ws, size_t ws_size,
                              hipStream_t stream) {
    const float* p1 = (const float*)d_in[0];
    const float* p2 = (const float*)d_in[1];
    const float* f1 = (const float*)d_in[2];
    const float* f2 = (const float*)d_in[3];
    const void*  idx = d_in[4];
    const float* W1 = (const float*)d_in[5];
    const float* g1 = (const float*)d_in[6];
    const float* b1 = (const float*)d_in[7];
    const float* W2 = (const float*)d_in[8];
    const float* g2 = (const float*)d_in[9];
    const float* b2 = (const float*)d_in[10];
    float* out = (float*)d_out;

    char* ws = (char*)d_ws;
    float* stats = (float*)(ws + STATS_OFF);
    float* sum1 = stats + 0;   float* ssq1 = stats + 256;
    float* scale1 = stats + 512; float* shift1 = stats + 768;
    float* sum2 = stats + 1024; float* ssq2 = stats + 1280;
    float* scale2 = stats + 1536; float* shift2 = stats + 1792;
    int* flag64 = (int*)(ws + FLAG_OFF);
    unsigned short* f2t = (unsigned short*)(ws + F2T_OFF);
    unsigned short* xT  = (unsigned short*)(ws + XT_OFF);
    unsigned short* h2  = (unsigned short*)(ws + H2_OFF);

    float* h1 = out;  // d_out reused as fp32 scratch for pre-BN h1; fully overwritten by k_apply

    k_init<<<1, 256, 0, stream>>>(idx, flag64, stats);
    k_tr_f2<<<dim3(MM / 32, C2 / 32, BB), dim3(32, 8), 0, stream>>>(f2, f2t);
    k_tr_f1<<<dim3(NN / 32, C1 / 32, BB), dim3(32, 8), 0, stream>>>(f1, xT);
    k_interp<<<MTOT / 8, 256, 0, stream>>>(p1, p2, idx, flag64, f2t, xT);
    k_gemm1<<<dim3(MTOT / Bb_M, CO / Bb_N), 256, 0, stream>>>(xT, W1, h1, sum1, ssq1);
    k_bnfin<<<1, 256, 0, stream>>>(sum1, ssq1, g1, b1, scale1, shift1);
    k_gemm2<<<dim3(MTOT / Bb_M, CO / Bb_N), 256, 0, stream>>>(h1, W2, scale1, shift1, h2, sum2, ssq2);
    k_bnfin<<<1, 256, 0, stream>>>(sum2, ssq2, g2, b2, scale2, shift2);
    k_apply<<<(int)((size_t)out_size / 4 / 256), 256, 0, stream>>>(h2, scale2, shift2, out);
}

// Round 2
// 433.000 us; speedup vs baseline: 2.1093x; 2.1093x over previous
//
#include <hip/hip_runtime.h>
#include <hip/hip_bf16.h>

// Problem constants
#define BB 8
#define NN 16384
#define MM 4096
#define C1 64
#define C2 256
#define K1 320            // C1 + C2
#define CO 256
#define MTOT (BB * NN)    // 131072

// Workspace layout (bytes)
#define STATS_OFF 0                 // 8*256 floats
#define FLAG_OFF  8192
#define W1B_OFF   16384             // bf16 256x320 = 163840 B
#define W2B_OFF   180224            // bf16 256x256 = 131072 B
#define F2T_OFF   327680            // bf16 [B,M,C2] = 16777216 B
#define XT_OFF    (327680 + 16777216)              // bf16 [MTOT,320] = 83886080 B
#define H2_OFF    (327680 + 16777216 + 83886080)   // bf16 [B,CO,N]  = 67108864 B

typedef short v8s __attribute__((ext_vector_type(8)));
typedef float v4f __attribute__((ext_vector_type(4)));

__device__ __forceinline__ float bf2f(unsigned short u) {
    unsigned v = ((unsigned)u) << 16;
    float f;
    __builtin_memcpy(&f, &v, 4);
    return f;
}
__device__ __forceinline__ unsigned short f2bf(float f) {
    unsigned u;
    __builtin_memcpy(&u, &f, 4);
    unsigned r = u + 0x7fffu + ((u >> 16) & 1u);  // RNE
    return (unsigned short)(r >> 16);
}
__device__ __forceinline__ void gload16(const unsigned short* g, unsigned short* l) {
    __builtin_amdgcn_global_load_lds((const __attribute__((address_space(1))) unsigned int*)g,
                                     (__attribute__((address_space(3))) unsigned int*)l, 16, 0, 0);
}

// ---------------- prep: zero stats, idx width flag, W1/W2 -> bf16 ----------
__global__ void k_prep(const void* idx_raw, int* flag64, float* stats,
                       const float* __restrict__ W1, unsigned short* __restrict__ W1b,
                       const float* __restrict__ W2, unsigned short* __restrict__ W2b) {
    int blk = blockIdx.x;
    int t = threadIdx.x;
    if (blk < 320) {                    // W1: 81920 elems
        int e = blk * 256 + t;
        W1b[e] = f2bf(W1[e]);
    } else if (blk < 576) {             // W2: 65536 elems
        int e = (blk - 320) * 256 + t;
        W2b[e] = f2bf(W2[e]);
    } else {
        for (int i = t; i < 8 * 256; i += 256) stats[i] = 0.f;
        if (t == 0) {
            const int* a = (const int*)idx_raw;
            int all0 = 1;
            for (int j = 1; j < 64; j += 2) all0 &= (a[j] == 0);
            *flag64 = all0;  // 1 => idx int64
        }
    }
}

// ---------------- tiled transpose f2 [B,C2,M] -> f2t bf16 [B,M,C2] ----------
__global__ void k_tr_f2(const float* __restrict__ f2, unsigned short* __restrict__ f2t) {
    __shared__ float tile[32][33];
    int b = blockIdx.z;
    int c0 = blockIdx.y * 32;
    int m0 = blockIdx.x * 32;
    int tx = threadIdx.x, ty = threadIdx.y;  // 32 x 8
    const float* src = f2 + ((size_t)b * C2 + c0) * MM + m0;
#pragma unroll
    for (int j = 0; j < 4; ++j)
        tile[ty + 8 * j][tx] = src[(size_t)(ty + 8 * j) * MM + tx];
    __syncthreads();
    unsigned short* dst = f2t + ((size_t)b * MM + m0) * C2 + c0;
#pragma unroll
    for (int j = 0; j < 4; ++j)
        dst[(size_t)(ty + 8 * j) * C2 + tx] = f2bf(tile[tx][ty + 8 * j]);
}

// ---------------- tiled transpose f1 [B,C1,N] -> xT[:,0:64] bf16 ------------
__global__ void k_tr_f1(const float* __restrict__ f1, unsigned short* __restrict__ xT) {
    __shared__ float tile[32][33];
    int b = blockIdx.z;
    int c0 = blockIdx.y * 32;
    int n0 = blockIdx.x * 32;
    int tx = threadIdx.x, ty = threadIdx.y;
    const float* src = f1 + ((size_t)b * C1 + c0) * NN + n0;
#pragma unroll
    for (int j = 0; j < 4; ++j)
        tile[ty + 8 * j][tx] = src[(size_t)(ty + 8 * j) * NN + tx];
    __syncthreads();
    unsigned short* dst = xT + ((size_t)b * NN + n0) * K1 + c0;
#pragma unroll
    for (int j = 0; j < 4; ++j)
        dst[(size_t)(ty + 8 * j) * K1 + tx] = f2bf(tile[tx][ty + 8 * j]);
}

// ---------------- 3-NN inverse-distance interpolation -> xT[:,64:320] -------
__global__ void k_interp(const float* __restrict__ p1, const float* __restrict__ p2,
                         const void* __restrict__ idxv, const int* __restrict__ flag64,
                         const unsigned short* __restrict__ f2t,
                         unsigned short* __restrict__ xT) {
    int t = threadIdx.x;
    int p = t >> 5, lane = t & 31;
    size_t pt = (size_t)blockIdx.x * 8 + p;
    int b = (int)(pt >> 14);
    int m0, m1, m2;
    if (*flag64) {
        const long long* id = (const long long*)idxv;
        m0 = (int)id[pt * 3 + 0]; m1 = (int)id[pt * 3 + 1]; m2 = (int)id[pt * 3 + 2];
    } else {
        const int* id = (const int*)idxv;
        m0 = id[pt * 3 + 0]; m1 = id[pt * 3 + 1]; m2 = id[pt * 3 + 2];
    }
    float qx = p1[pt * 3 + 0], qy = p1[pt * 3 + 1], qz = p1[pt * 3 + 2];
    const float* pb = p2 + (size_t)b * MM * 3;
    float dx, dy, dz;
    dx = qx - pb[m0 * 3 + 0]; dy = qy - pb[m0 * 3 + 1]; dz = qz - pb[m0 * 3 + 2];
    float d0 = dx * dx + dy * dy + dz * dz;
    dx = qx - pb[m1 * 3 + 0]; dy = qy - pb[m1 * 3 + 1]; dz = qz - pb[m1 * 3 + 2];
    float d1 = dx * dx + dy * dy + dz * dz;
    dx = qx - pb[m2 * 3 + 0]; dy = qy - pb[m2 * 3 + 1]; dz = qz - pb[m2 * 3 + 2];
    float d2v = dx * dx + dy * dy + dz * dz;
    float r0 = 1.f / (d0 + 1e-8f), r1 = 1.f / (d1 + 1e-8f), r2 = 1.f / (d2v + 1e-8f);
    float inv = 1.f / (r0 + r1 + r2);
    float w0 = r0 * inv, w1 = r1 * inv, w2 = r2 * inv;

    const unsigned short* fb = f2t + (size_t)b * MM * C2;
    int c0 = lane * 8;
    uint4 va = *(const uint4*)(fb + (size_t)m0 * C2 + c0);
    uint4 vb = *(const uint4*)(fb + (size_t)m1 * C2 + c0);
    uint4 vc = *(const uint4*)(fb + (size_t)m2 * C2 + c0);

    float r[8];
    {
        const unsigned av[4] = {va.x, va.y, va.z, va.w};
        const unsigned bv[4] = {vb.x, vb.y, vb.z, vb.w};
        const unsigned cv[4] = {vc.x, vc.y, vc.z, vc.w};
#pragma unroll
        for (int q = 0; q < 4; ++q) {
            r[2 * q + 0] = w0 * bf2f((unsigned short)(av[q] & 0xffff))
                         + w1 * bf2f((unsigned short)(bv[q] & 0xffff))
                         + w2 * bf2f((unsigned short)(cv[q] & 0xffff));
            r[2 * q + 1] = w0 * bf2f((unsigned short)(av[q] >> 16))
                         + w1 * bf2f((unsigned short)(bv[q] >> 16))
                         + w2 * bf2f((unsigned short)(cv[q] >> 16));
        }
    }
    uint4 outv;
    outv.x = (unsigned)f2bf(r[0]) | ((unsigned)f2bf(r[1]) << 16);
    outv.y = (unsigned)f2bf(r[2]) | ((unsigned)f2bf(r[3]) << 16);
    outv.z = (unsigned)f2bf(r[4]) | ((unsigned)f2bf(r[5]) << 16);
    outv.w = (unsigned)f2bf(r[6]) | ((unsigned)f2bf(r[7]) << 16);
    *(uint4*)(xT + pt * K1 + C1 + c0) = outv;
}

// ================= MFMA GEMM1: h1 = xT @ W1^T (bf16), + BN1 stats ==========
#define TM 128
#define TN 128
#define TK 64
__launch_bounds__(256)
__global__ void k_gemm1(const unsigned short* __restrict__ xT,
                        const unsigned short* __restrict__ W1b,
                        unsigned short* __restrict__ h1,
                        float* __restrict__ sum1, float* __restrict__ ssq1) {
    __shared__ unsigned short As[TM * TK];
    __shared__ unsigned short Bs[TN * TK];
    __shared__ float s_sum[TN], s_ssq[TN];
    const int t = threadIdx.x;
    const int lane = t & 63, w = t >> 6;
    const int wm = w >> 1, wc = w & 1;
    const long rbase = (long)blockIdx.x * TM;
    const int cb = blockIdx.y * TN;

    if (t < TN) { s_sum[t] = 0.f; s_ssq[t] = 0.f; }

    v4f acc[4][4];
#pragma unroll
    for (int r = 0; r < 4; ++r)
#pragma unroll
        for (int c = 0; c < 4; ++c) acc[r][c] = (v4f)(0.f);

    const int srow = w * 32 + (lane >> 3);   // staging row (+ j*8)
    const int sch = (lane & 7) * 8;          // k chunk
    const unsigned short* Ag = xT + (rbase + srow) * K1 + sch;
    const unsigned short* Bg = W1b + (size_t)(cb + srow) * K1 + sch;

    for (int k0 = 0; k0 < K1; k0 += TK) {
#pragma unroll
        for (int j = 0; j < 4; ++j) {
            gload16(Ag + (size_t)(j * 8) * K1 + k0, As + (w * 32 + j * 8) * TK);
            gload16(Bg + (size_t)(j * 8) * K1 + k0, Bs + (w * 32 + j * 8) * TK);
        }
        __syncthreads();
        const unsigned short* ApL = As + (wm * 64 + (lane & 15)) * TK + (lane >> 4) * 8;
        const unsigned short* BpL = Bs + (wc * 64 + (lane & 15)) * TK + (lane >> 4) * 8;
#pragma unroll
        for (int ks = 0; ks < 2; ++ks) {
            v8s af[4], bg[4];
#pragma unroll
            for (int r = 0; r < 4; ++r) af[r] = *(const v8s*)(ApL + r * 16 * TK + ks * 32);
#pragma unroll
            for (int c = 0; c < 4; ++c) bg[c] = *(const v8s*)(BpL + c * 16 * TK + ks * 32);
#pragma unroll
            for (int r = 0; r < 4; ++r)
#pragma unroll
                for (int c = 0; c < 4; ++c)
                    acc[r][c] = __builtin_amdgcn_mfma_f32_16x16x32_bf16(af[r], bg[c], acc[r][c], 0, 0, 0);
        }
        __syncthreads();
    }

    const int q = lane >> 4, ln = lane & 15;
#pragma unroll
    for (int c = 0; c < 4; ++c) {
        int col = cb + wc * 64 + c * 16 + ln;
        float s = 0.f, sq = 0.f;
#pragma unroll
        for (int r = 0; r < 4; ++r) {
            long row = rbase + wm * 64 + r * 16 + q * 4;
#pragma unroll
            for (int i = 0; i < 4; ++i) {
                float v = acc[r][c][i];
                h1[(size_t)(row + i) * CO + col] = f2bf(v);
                s += v; sq += v * v;
            }
        }
        atomicAdd(&s_sum[wc * 64 + c * 16 + ln], s);
        atomicAdd(&s_ssq[wc * 64 + c * 16 + ln], sq);
    }
    __syncthreads();
    if (t < TN) {
        atomicAdd(&sum1[cb + t], s_sum[t]);
        atomicAdd(&ssq1[cb + t], s_ssq[t]);
    }
}

// ---------------- BN finalize ----------------------------------------------
__global__ void k_bnfin(const float* __restrict__ sum, const float* __restrict__ ssq,
                        const float* __restrict__ g, const float* __restrict__ bb,
                        float* __restrict__ scale, float* __restrict__ shift) {
    int c = threadIdx.x;
    const float invn = 1.f / (float)MTOT;
    float m = sum[c] * invn;
    float v = ssq[c] * invn - m * m;
    float s = g[c] * rsqrtf(v + 1e-5f);
    scale[c] = s;
    shift[c] = bb[c] - m * s;
}

// ====== MFMA GEMM2: h2 = relu(bn1(h1)) @ W2^T, h2 in [B,CO,N] + BN2 stats ===
__launch_bounds__(256)
__global__ void k_gemm2(const unsigned short* __restrict__ h1,
                        const unsigned short* __restrict__ W2b,
                        const float* __restrict__ scale1, const float* __restrict__ shift1,
                        unsigned short* __restrict__ h2,
                        float* __restrict__ sum2, float* __restrict__ ssq2) {
    __shared__ unsigned short As[TM * TK];
    __shared__ unsigned short Bs[TN * TK];
    __shared__ float s_sum[TN], s_ssq[TN];
    const int t = threadIdx.x;
    const int lane = t & 63, w = t >> 6;
    const int wm = w >> 1, wc = w & 1;
    const long rbase = (long)blockIdx.x * TM;
    const int cb = blockIdx.y * TN;

    if (t < TN) { s_sum[t] = 0.f; s_ssq[t] = 0.f; }

    v4f acc[4][4];
#pragma unroll
    for (int r = 0; r < 4; ++r)
#pragma unroll
        for (int c = 0; c < 4; ++c) acc[r][c] = (v4f)(0.f);

    const int srow = w * 32 + (lane >> 3);
    const int sch = (lane & 7) * 8;
    const unsigned short* Ag = h1 + (rbase + srow) * CO + sch;
    const unsigned short* Bg = W2b + (size_t)(cb + srow) * CO + sch;
    unsigned short* AsW = As + (srow)*TK + sch;   // this thread's LDS slot for A

    for (int k0 = 0; k0 < CO; k0 += TK) {
#pragma unroll
        for (int j = 0; j < 4; ++j)
            gload16(Bg + (size_t)(j * 8) * CO + k0, Bs + (w * 32 + j * 8) * TK);
        // A path: load, BN1+ReLU, repack to bf16, ds_write
        float4 sca = *(const float4*)(scale1 + k0 + sch);
        float4 scb = *(const float4*)(scale1 + k0 + sch + 4);
        float4 sha = *(const float4*)(shift1 + k0 + sch);
        float4 shb = *(const float4*)(shift1 + k0 + sch + 4);
#pragma unroll
        for (int j = 0; j < 4; ++j) {
            uint4 av = *(const uint4*)(Ag + (size_t)(j * 8) * CO + k0);
            float y0 = fmaxf(bf2f((unsigned short)(av.x & 0xffff)) * sca.x + sha.x, 0.f);
            float y1 = fmaxf(bf2f((unsigned short)(av.x >> 16)) * sca.y + sha.y, 0.f);
            float y2 = fmaxf(bf2f((unsigned short)(av.y & 0xffff)) * sca.z + sha.z, 0.f);
            float y3 = fmaxf(bf2f((unsigned short)(av.y >> 16)) * sca.w + sha.w, 0.f);
            float y4 = fmaxf(bf2f((unsigned short)(av.z & 0xffff)) * scb.x + shb.x, 0.f);
            float y5 = fmaxf(bf2f((unsigned short)(av.z >> 16)) * scb.y + shb.y, 0.f);
            float y6 = fmaxf(bf2f((unsigned short)(av.w & 0xffff)) * scb.z + shb.z, 0.f);
            float y7 = fmaxf(bf2f((unsigned short)(av.w >> 16)) * scb.w + shb.w, 0.f);
            uint4 ov;
            ov.x = (unsigned)f2bf(y0) | ((unsigned)f2bf(y1) << 16);
            ov.y = (unsigned)f2bf(y2) | ((unsigned)f2bf(y3) << 16);
            ov.z = (unsigned)f2bf(y4) | ((unsigned)f2bf(y5) << 16);
            ov.w = (unsigned)f2bf(y6) | ((unsigned)f2bf(y7) << 16);
            *(uint4*)(AsW + (j * 8) * TK) = ov;
        }
        __syncthreads();
        const unsigned short* ApL = As + (wm * 64 + (lane & 15)) * TK + (lane >> 4) * 8;
        const unsigned short* BpL = Bs + (wc * 64 + (lane & 15)) * TK + (lane >> 4) * 8;
#pragma unroll
        for (int ks = 0; ks < 2; ++ks) {
            v8s af[4], bg4[4];
#pragma unroll
            for (int r = 0; r < 4; ++r) af[r] = *(const v8s*)(ApL + r * 16 * TK + ks * 32);
#pragma unroll
            for (int c = 0; c < 4; ++c) bg4[c] = *(const v8s*)(BpL + c * 16 * TK + ks * 32);
#pragma unroll
            for (int r = 0; r < 4; ++r)
#pragma unroll
                for (int c = 0; c < 4; ++c)
                    acc[r][c] = __builtin_amdgcn_mfma_f32_16x16x32_bf16(af[r], bg4[c], acc[r][c], 0, 0, 0);
        }
        __syncthreads();
    }

    const int q = lane >> 4, ln = lane & 15;
    const int b = (int)(rbase >> 14);
    const int nb = (int)(rbase & (NN - 1)) + wm * 64;
#pragma unroll
    for (int c = 0; c < 4; ++c) {
        int o = cb + wc * 64 + c * 16 + ln;
        unsigned short* hp = h2 + (((size_t)(b * CO + o)) << 14);
        float s = 0.f, sq = 0.f;
#pragma unroll
        for (int r = 0; r < 4; ++r) {
            int n0 = nb + r * 16 + q * 4;
            float v0 = acc[r][c][0], v1 = acc[r][c][1], v2 = acc[r][c][2], v3 = acc[r][c][3];
            ushort4 hv;
            hv.x = f2bf(v0); hv.y = f2bf(v1); hv.z = f2bf(v2); hv.w = f2bf(v3);
            *(ushort4*)(hp + n0) = hv;
            s += v0 + v1 + v2 + v3;
            sq += v0 * v0 + v1 * v1 + v2 * v2 + v3 * v3;
        }
        atomicAdd(&s_sum[wc * 64 + c * 16 + ln], s);
        atomicAdd(&s_ssq[wc * 64 + c * 16 + ln], sq);
    }
    __syncthreads();
    if (t < TN) {
        atomicAdd(&sum2[cb + t], s_sum[t]);
        atomicAdd(&ssq2[cb + t], s_ssq[t]);
    }
}

// ---------------- final elementwise BN2+ReLU -> fp32 out --------------------
__global__ void k_apply(const unsigned short* __restrict__ h2,
                        const float* __restrict__ scale2, const float* __restrict__ shift2,
                        float* __restrict__ out) {
    size_t i = ((size_t)blockIdx.x * 256 + threadIdx.x) * 4;
    int o = (int)((i >> 14) & 255);
    float s = scale2[o], d = shift2[o];
    ushort4 hv = *(const ushort4*)(h2 + i);
    float4 v;
    v.x = fmaxf(bf2f(hv.x) * s + d, 0.f);
    v.y = fmaxf(bf2f(hv.y) * s + d, 0.f);
    v.z = fmaxf(bf2f(hv.z) * s + d, 0.f);
    v.w = fmaxf(bf2f(hv.w) * s + d, 0.f);
    *(float4*)&out[i] = v;
}

extern "C" void kernel_launch(void* const* d_in, const int* in_sizes, int n_in,
                              void* d_out, int out_size, void* d_ws, size_t ws_size,
                              hipStream_t stream) {
    const float* p1 = (const float*)d_in[0];
    const float* p2 = (const float*)d_in[1];
    const float* f1 = (const float*)d_in[2];
    const float* f2 = (const float*)d_in[3];
    const void*  idx = d_in[4];
    const float* W1 = (const float*)d_in[5];
    const float* g1 = (const float*)d_in[6];
    const float* b1 = (const float*)d_in[7];
    const float* W2 = (const float*)d_in[8];
    const float* g2 = (const float*)d_in[9];
    const float* b2 = (const float*)d_in[10];
    float* out = (float*)d_out;

    char* ws = (char*)d_ws;
    float* stats = (float*)(ws + STATS_OFF);
    float* sum1 = stats + 0;     float* ssq1 = stats + 256;
    float* scale1 = stats + 512; float* shift1 = stats + 768;
    float* sum2 = stats + 1024;  float* ssq2 = stats + 1280;
    float* scale2 = stats + 1536; float* shift2 = stats + 1792;
    int* flag64 = (int*)(ws + FLAG_OFF);
    unsigned short* W1b = (unsigned short*)(ws + W1B_OFF);
    unsigned short* W2b = (unsigned short*)(ws + W2B_OFF);
    unsigned short* f2t = (unsigned short*)(ws + F2T_OFF);
    unsigned short* xT  = (unsigned short*)(ws + XT_OFF);
    unsigned short* h2  = (unsigned short*)(ws + H2_OFF);

    // h1 (bf16, 67 MB) parked in d_out (134 MB, fully overwritten by k_apply)
    unsigned short* h1 = (unsigned short*)d_out;

    k_prep<<<577, 256, 0, stream>>>(idx, flag64, stats, W1, W1b, W2, W2b);
    k_tr_f2<<<dim3(MM / 32, C2 / 32, BB), dim3(32, 8), 0, stream>>>(f2, f2t);
    k_tr_f1<<<dim3(NN / 32, C1 / 32, BB), dim3(32, 8), 0, stream>>>(f1, xT);
    k_interp<<<MTOT / 8, 256, 0, stream>>>(p1, p2, idx, flag64, f2t, xT);
    k_gemm1<<<dim3(MTOT / TM, CO / TN), 256, 0, stream>>>(xT, W1b, h1, sum1, ssq1);
    k_bnfin<<<1, 256, 0, stream>>>(sum1, ssq1, g1, b1, scale1, shift1);
    k_gemm2<<<dim3(MTOT / TM, CO / TN), 256, 0, stream>>>(h1, W2b, scale1, shift1, h2, sum2, ssq2);
    k_bnfin<<<1, 256, 0, stream>>>(sum2, ssq2, g2, b2, scale2, shift2);
    k_apply<<<(int)((size_t)out_size / 4 / 256), 256, 0, stream>>>(h2, scale2, shift2, out);
}

// Round 3
// 425.924 us; speedup vs baseline: 2.1444x; 1.0166x over previous
//
#include <hip/hip_runtime.h>
#include <hip/hip_bf16.h>

// Problem constants
#define BB 8
#define NN 16384
#define MM 4096
#define C1 64
#define C2 256
#define K1 320            // C1 + C2
#define CO 256
#define MTOT (BB * NN)    // 131072

// Workspace layout (bytes)
#define STATS_OFF 0                 // 8*256 floats
#define FLAG_OFF  8192
#define W1B_OFF   16384             // bf16 256x320
#define W2B_OFF   180224            // bf16 256x256
#define F2T_OFF   327680            // bf16 [B,M,C2] = 16777216 B
#define XT_OFF    (327680 + 16777216)              // bf16 [MTOT,320]
#define H2_OFF    (327680 + 16777216 + 83886080)   // bf16 [B,CO,N]

typedef short v8s __attribute__((ext_vector_type(8)));
typedef float v4f __attribute__((ext_vector_type(4)));

__device__ __forceinline__ float bf2f(unsigned short u) {
    unsigned v = ((unsigned)u) << 16;
    float f;
    __builtin_memcpy(&f, &v, 4);
    return f;
}
__device__ __forceinline__ unsigned short f2bf(float f) {
    unsigned u;
    __builtin_memcpy(&u, &f, 4);
    unsigned r = u + 0x7fffu + ((u >> 16) & 1u);  // RNE
    return (unsigned short)(r >> 16);
}
__device__ __forceinline__ void gload16(const unsigned short* g, unsigned short* l) {
    __builtin_amdgcn_global_load_lds((const __attribute__((address_space(1))) unsigned int*)g,
                                     (__attribute__((address_space(3))) unsigned int*)l, 16, 0, 0);
}

// ---------------- prep: zero stats, idx width flag, W1/W2 -> bf16 ----------
__global__ void k_prep(const void* idx_raw, int* flag64, float* stats,
                       const float* __restrict__ W1, unsigned short* __restrict__ W1b,
                       const float* __restrict__ W2, unsigned short* __restrict__ W2b) {
    int blk = blockIdx.x;
    int t = threadIdx.x;
    if (blk < 320) {
        int e = blk * 256 + t;
        W1b[e] = f2bf(W1[e]);
    } else if (blk < 576) {
        int e = (blk - 320) * 256 + t;
        W2b[e] = f2bf(W2[e]);
    } else {
        for (int i = t; i < 8 * 256; i += 256) stats[i] = 0.f;
        if (t == 0) {
            const int* a = (const int*)idx_raw;
            int all0 = 1;
            for (int j = 1; j < 64; j += 2) all0 &= (a[j] == 0);
            *flag64 = all0;  // 1 => idx int64
        }
    }
}

// ------- transpose f2 [B,C2,M] -> f2t bf16 [B,M,C2]; 64ch x 32m tiles ------
__global__ void k_tr_f2(const float* __restrict__ f2, unsigned short* __restrict__ f2t) {
    __shared__ float tile[64][33];
    int b = blockIdx.z;
    int c0 = blockIdx.y * 64;
    int m0 = blockIdx.x * 32;
    int t = threadIdx.x;
    int lm = t & 31, lc = t >> 5;          // lc 0..7
    const float* src = f2 + ((size_t)b * C2 + c0) * MM + m0;
#pragma unroll
    for (int j = 0; j < 8; ++j)
        tile[lc + 8 * j][lm] = src[(size_t)(lc + 8 * j) * MM + lm];
    __syncthreads();
    int m = t >> 3, c8 = (t & 7) * 8;      // m 0..31, c8 0..56
    unsigned short tmp[8];
#pragma unroll
    for (int k = 0; k < 8; ++k) tmp[k] = f2bf(tile[c8 + k][m]);
    uint4 v;
    v.x = (unsigned)tmp[0] | ((unsigned)tmp[1] << 16);
    v.y = (unsigned)tmp[2] | ((unsigned)tmp[3] << 16);
    v.z = (unsigned)tmp[4] | ((unsigned)tmp[5] << 16);
    v.w = (unsigned)tmp[6] | ((unsigned)tmp[7] << 16);
    *(uint4*)&f2t[((size_t)b * MM + m0 + m) * C2 + c0 + c8] = v;
}

// ------- transpose f1 [B,C1,N] -> xT[:,0:64] bf16; 64ch x 32n tiles --------
__global__ void k_tr_f1(const float* __restrict__ f1, unsigned short* __restrict__ xT) {
    __shared__ float tile[64][33];
    int b = blockIdx.z;
    int n0 = blockIdx.x * 32;
    int t = threadIdx.x;
    int lm = t & 31, lc = t >> 5;
    const float* src = f1 + ((size_t)b * C1) * NN + n0;
#pragma unroll
    for (int j = 0; j < 8; ++j)
        tile[lc + 8 * j][lm] = src[(size_t)(lc + 8 * j) * NN + lm];
    __syncthreads();
    int m = t >> 3, c8 = (t & 7) * 8;
    unsigned short tmp[8];
#pragma unroll
    for (int k = 0; k < 8; ++k) tmp[k] = f2bf(tile[c8 + k][m]);
    uint4 v;
    v.x = (unsigned)tmp[0] | ((unsigned)tmp[1] << 16);
    v.y = (unsigned)tmp[2] | ((unsigned)tmp[3] << 16);
    v.z = (unsigned)tmp[4] | ((unsigned)tmp[5] << 16);
    v.w = (unsigned)tmp[6] | ((unsigned)tmp[7] << 16);
    *(uint4*)&xT[((size_t)b * NN + n0 + m) * K1 + c8] = v;
}

// ---------------- 3-NN inverse-distance interpolation -> xT[:,64:320] -------
__global__ void k_interp(const float* __restrict__ p1, const float* __restrict__ p2,
                         const void* __restrict__ idxv, const int* __restrict__ flag64,
                         const unsigned short* __restrict__ f2t,
                         unsigned short* __restrict__ xT) {
    int t = threadIdx.x;
    int p = t >> 5, lane = t & 31;
    size_t pt = (size_t)blockIdx.x * 8 + p;
    int b = (int)(pt >> 14);
    int m0, m1, m2;
    if (*flag64) {
        const long long* id = (const long long*)idxv;
        m0 = (int)id[pt * 3 + 0]; m1 = (int)id[pt * 3 + 1]; m2 = (int)id[pt * 3 + 2];
    } else {
        const int* id = (const int*)idxv;
        m0 = id[pt * 3 + 0]; m1 = id[pt * 3 + 1]; m2 = id[pt * 3 + 2];
    }
    float qx = p1[pt * 3 + 0], qy = p1[pt * 3 + 1], qz = p1[pt * 3 + 2];
    const float* pb = p2 + (size_t)b * MM * 3;
    float dx, dy, dz;
    dx = qx - pb[m0 * 3 + 0]; dy = qy - pb[m0 * 3 + 1]; dz = qz - pb[m0 * 3 + 2];
    float d0 = dx * dx + dy * dy + dz * dz;
    dx = qx - pb[m1 * 3 + 0]; dy = qy - pb[m1 * 3 + 1]; dz = qz - pb[m1 * 3 + 2];
    float d1 = dx * dx + dy * dy + dz * dz;
    dx = qx - pb[m2 * 3 + 0]; dy = qy - pb[m2 * 3 + 1]; dz = qz - pb[m2 * 3 + 2];
    float d2v = dx * dx + dy * dy + dz * dz;
    float r0 = 1.f / (d0 + 1e-8f), r1 = 1.f / (d1 + 1e-8f), r2 = 1.f / (d2v + 1e-8f);
    float inv = 1.f / (r0 + r1 + r2);
    float w0 = r0 * inv, w1 = r1 * inv, w2 = r2 * inv;

    const unsigned short* fb = f2t + (size_t)b * MM * C2;
    int c0 = lane * 8;
    uint4 va = *(const uint4*)(fb + (size_t)m0 * C2 + c0);
    uint4 vb = *(const uint4*)(fb + (size_t)m1 * C2 + c0);
    uint4 vc = *(const uint4*)(fb + (size_t)m2 * C2 + c0);

    float r[8];
    {
        const unsigned av[4] = {va.x, va.y, va.z, va.w};
        const unsigned bv[4] = {vb.x, vb.y, vb.z, vb.w};
        const unsigned cv[4] = {vc.x, vc.y, vc.z, vc.w};
#pragma unroll
        for (int q = 0; q < 4; ++q) {
            r[2 * q + 0] = w0 * bf2f((unsigned short)(av[q] & 0xffff))
                         + w1 * bf2f((unsigned short)(bv[q] & 0xffff))
                         + w2 * bf2f((unsigned short)(cv[q] & 0xffff));
            r[2 * q + 1] = w0 * bf2f((unsigned short)(av[q] >> 16))
                         + w1 * bf2f((unsigned short)(bv[q] >> 16))
                         + w2 * bf2f((unsigned short)(cv[q] >> 16));
        }
    }
    uint4 outv;
    outv.x = (unsigned)f2bf(r[0]) | ((unsigned)f2bf(r[1]) << 16);
    outv.y = (unsigned)f2bf(r[2]) | ((unsigned)f2bf(r[3]) << 16);
    outv.z = (unsigned)f2bf(r[4]) | ((unsigned)f2bf(r[5]) << 16);
    outv.w = (unsigned)f2bf(r[6]) | ((unsigned)f2bf(r[7]) << 16);
    *(uint4*)(xT + pt * K1 + C1 + c0) = outv;
}

// ================= MFMA GEMM1: h1 = xT @ W1^T (bf16), + BN1 stats ==========
#define TM 128
#define TN 128
#define TK 64
__launch_bounds__(256)
__global__ void k_gemm1(const unsigned short* __restrict__ xT,
                        const unsigned short* __restrict__ W1b,
                        unsigned short* __restrict__ h1,
                        float* __restrict__ sum1, float* __restrict__ ssq1) {
    __shared__ unsigned short smem[TM * TK + TN * TK];   // As | Bs, reused as 128x128 epilogue tile
    __shared__ float s_sum[TN], s_ssq[TN];
    unsigned short* As = smem;
    unsigned short* Bs = smem + TM * TK;
    const int t = threadIdx.x;
    const int lane = t & 63, w = t >> 6;
    const int wm = w >> 1, wc = w & 1;
    const long rbase = (long)blockIdx.x * TM;
    const int cb = blockIdx.y * TN;

    if (t < TN) { s_sum[t] = 0.f; s_ssq[t] = 0.f; }

    v4f acc[4][4];
#pragma unroll
    for (int r = 0; r < 4; ++r)
#pragma unroll
        for (int c = 0; c < 4; ++c) acc[r][c] = (v4f)(0.f);

    const int srow = w * 32 + (lane >> 3);
    const int sch = (lane & 7) * 8;
    const unsigned short* Ag = xT + (rbase + srow) * K1 + sch;
    const unsigned short* Bg = W1b + (size_t)(cb + srow) * K1 + sch;

    for (int k0 = 0; k0 < K1; k0 += TK) {
#pragma unroll
        for (int j = 0; j < 4; ++j) {
            gload16(Ag + (size_t)(j * 8) * K1 + k0, As + (w * 32 + j * 8) * TK);
            gload16(Bg + (size_t)(j * 8) * K1 + k0, Bs + (w * 32 + j * 8) * TK);
        }
        __syncthreads();
        const unsigned short* ApL = As + (wm * 64 + (lane & 15)) * TK + (lane >> 4) * 8;
        const unsigned short* BpL = Bs + (wc * 64 + (lane & 15)) * TK + (lane >> 4) * 8;
#pragma unroll
        for (int ks = 0; ks < 2; ++ks) {
            v8s af[4], bg[4];
#pragma unroll
            for (int r = 0; r < 4; ++r) af[r] = *(const v8s*)(ApL + r * 16 * TK + ks * 32);
#pragma unroll
            for (int c = 0; c < 4; ++c) bg[c] = *(const v8s*)(BpL + c * 16 * TK + ks * 32);
#pragma unroll
            for (int r = 0; r < 4; ++r)
#pragma unroll
                for (int c = 0; c < 4; ++c)
                    acc[r][c] = __builtin_amdgcn_mfma_f32_16x16x32_bf16(af[r], bg[c], acc[r][c], 0, 0, 0);
        }
        __syncthreads();
    }

    // ---- epilogue: stats + XOR-swizzled LDS transpose -> coalesced stores ----
    const int q = lane >> 4, ln = lane & 15;
#pragma unroll
    for (int c = 0; c < 4; ++c) {
        int col = wc * 64 + c * 16 + ln;            // local col 0..127
        int cc = col >> 3, ci = col & 7;
        float s = 0.f, sq = 0.f;
#pragma unroll
        for (int r = 0; r < 4; ++r)
#pragma unroll
            for (int i = 0; i < 4; ++i) {
                int row = wm * 64 + r * 16 + q * 4 + i;
                float v = acc[r][c][i];
                smem[row * 128 + 8 * (cc ^ (row & 15)) + ci] = f2bf(v);
                s += v; sq += v * v;
            }
        atomicAdd(&s_sum[col], s);
        atomicAdd(&s_ssq[col], sq);
    }
    __syncthreads();
    {
        int rr = t >> 4, cc2 = t & 15;
#pragma unroll
        for (int j = 0; j < 8; ++j) {
            int row = rr + 16 * j;
            uint4 v = *(const uint4*)&smem[row * 128 + 8 * (cc2 ^ (row & 15))];
            *(uint4*)&h1[(size_t)(rbase + row) * CO + cb + cc2 * 8] = v;
        }
    }
    if (t < TN) {
        atomicAdd(&sum1[cb + t], s_sum[t]);
        atomicAdd(&ssq1[cb + t], s_ssq[t]);
    }
}

// ====== MFMA GEMM2: h2 = relu(bn1(h1)) @ W2^T -> [B,CO,N] + BN2 stats =======
__launch_bounds__(256)
__global__ void k_gemm2(const unsigned short* __restrict__ h1,
                        const unsigned short* __restrict__ W2b,
                        const float* __restrict__ sum1, const float* __restrict__ ssq1,
                        const float* __restrict__ g1, const float* __restrict__ b1,
                        unsigned short* __restrict__ h2,
                        float* __restrict__ sum2, float* __restrict__ ssq2) {
    __shared__ unsigned short smem[TM * TK + TN * TK];
    __shared__ float s_sum[TN], s_ssq[TN];
    __shared__ float sc1[CO], sh1[CO];
    unsigned short* As = smem;
    unsigned short* Bs = smem + TM * TK;
    const int t = threadIdx.x;
    const int lane = t & 63, w = t >> 6;
    const int wm = w >> 1, wc = w & 1;
    const long rbase = (long)blockIdx.x * TM;
    const int cb = blockIdx.y * TN;

    // fold BN1 finalize: per-block compute of scale/shift (stream-ordered after gemm1)
    {
        const float invn = 1.f / (float)MTOT;
        float m = sum1[t] * invn;
        float v = ssq1[t] * invn - m * m;
        float s = g1[t] * rsqrtf(v + 1e-5f);
        sc1[t] = s;
        sh1[t] = b1[t] - m * s;
    }
    if (t < TN) { s_sum[t] = 0.f; s_ssq[t] = 0.f; }
    __syncthreads();

    v4f acc[4][4];
#pragma unroll
    for (int r = 0; r < 4; ++r)
#pragma unroll
        for (int c = 0; c < 4; ++c) acc[r][c] = (v4f)(0.f);

    const int srow = w * 32 + (lane >> 3);
    const int sch = (lane & 7) * 8;
    const unsigned short* Ag = h1 + (rbase + srow) * CO + sch;
    const unsigned short* Bg = W2b + (size_t)(cb + srow) * CO + sch;
    unsigned short* AsW = As + srow * TK + sch;

    for (int k0 = 0; k0 < CO; k0 += TK) {
#pragma unroll
        for (int j = 0; j < 4; ++j)
            gload16(Bg + (size_t)(j * 8) * CO + k0, Bs + (w * 32 + j * 8) * TK);
        float4 sca = *(const float4*)(sc1 + k0 + sch);
        float4 scb = *(const float4*)(sc1 + k0 + sch + 4);
        float4 sha = *(const float4*)(sh1 + k0 + sch);
        float4 shb = *(const float4*)(sh1 + k0 + sch + 4);
#pragma unroll
        for (int j = 0; j < 4; ++j) {
            uint4 av = *(const uint4*)(Ag + (size_t)(j * 8) * CO + k0);
            float y0 = fmaxf(bf2f((unsigned short)(av.x & 0xffff)) * sca.x + sha.x, 0.f);
            float y1 = fmaxf(bf2f((unsigned short)(av.x >> 16)) * sca.y + sha.y, 0.f);
            float y2 = fmaxf(bf2f((unsigned short)(av.y & 0xffff)) * sca.z + sha.z, 0.f);
            float y3 = fmaxf(bf2f((unsigned short)(av.y >> 16)) * sca.w + sha.w, 0.f);
            float y4 = fmaxf(bf2f((unsigned short)(av.z & 0xffff)) * scb.x + shb.x, 0.f);
            float y5 = fmaxf(bf2f((unsigned short)(av.z >> 16)) * scb.y + shb.y, 0.f);
            float y6 = fmaxf(bf2f((unsigned short)(av.w & 0xffff)) * scb.z + shb.z, 0.f);
            float y7 = fmaxf(bf2f((unsigned short)(av.w >> 16)) * scb.w + shb.w, 0.f);
            uint4 ov;
            ov.x = (unsigned)f2bf(y0) | ((unsigned)f2bf(y1) << 16);
            ov.y = (unsigned)f2bf(y2) | ((unsigned)f2bf(y3) << 16);
            ov.z = (unsigned)f2bf(y4) | ((unsigned)f2bf(y5) << 16);
            ov.w = (unsigned)f2bf(y6) | ((unsigned)f2bf(y7) << 16);
            *(uint4*)(AsW + (j * 8) * TK) = ov;
        }
        __syncthreads();
        const unsigned short* ApL = As + (wm * 64 + (lane & 15)) * TK + (lane >> 4) * 8;
        const unsigned short* BpL = Bs + (wc * 64 + (lane & 15)) * TK + (lane >> 4) * 8;
#pragma unroll
        for (int ks = 0; ks < 2; ++ks) {
            v8s af[4], bg4[4];
#pragma unroll
            for (int r = 0; r < 4; ++r) af[r] = *(const v8s*)(ApL + r * 16 * TK + ks * 32);
#pragma unroll
            for (int c = 0; c < 4; ++c) bg4[c] = *(const v8s*)(BpL + c * 16 * TK + ks * 32);
#pragma unroll
            for (int r = 0; r < 4; ++r)
#pragma unroll
                for (int c = 0; c < 4; ++c)
                    acc[r][c] = __builtin_amdgcn_mfma_f32_16x16x32_bf16(af[r], bg4[c], acc[r][c], 0, 0, 0);
        }
        __syncthreads();
    }

    // ---- epilogue: stats + transposed swizzled tile -> n-contiguous stores ----
    const int q = lane >> 4, ln = lane & 15;
    const int b = (int)(rbase >> 14);
    const int nb = (int)(rbase & (NN - 1));
#pragma unroll
    for (int c = 0; c < 4; ++c) {
        int ol = wc * 64 + c * 16 + ln;             // local out-channel 0..127
        float s = 0.f, sq = 0.f;
#pragma unroll
        for (int r = 0; r < 4; ++r)
#pragma unroll
            for (int i = 0; i < 4; ++i) {
                int row = wm * 64 + r * 16 + q * 4 + i;  // local n
                int rc = row >> 3, ri = row & 7;
                float v = acc[r][c][i];
                smem[ol * 128 + 8 * (rc ^ (ol & 15)) + ri] = f2bf(v);
                s += v; sq += v * v;
            }
        atomicAdd(&s_sum[ol], s);
        atomicAdd(&s_ssq[ol], sq);
    }
    __syncthreads();
    {
        int oo = t >> 4, nc = t & 15;
#pragma unroll
        for (int j = 0; j < 8; ++j) {
            int ol = oo + 16 * j;
            uint4 v = *(const uint4*)&smem[ol * 128 + 8 * (nc ^ (ol & 15))];
            *(uint4*)&h2[(((size_t)(b * CO + cb + ol)) << 14) + nb + nc * 8] = v;
        }
    }
    if (t < TN) {
        atomicAdd(&sum2[cb + t], s_sum[t]);
        atomicAdd(&ssq2[cb + t], s_ssq[t]);
    }
}

// ---------------- final BN2+ReLU -> fp32 out (BN2 finalize folded) ----------
__global__ void k_apply(const unsigned short* __restrict__ h2,
                        const float* __restrict__ sum2, const float* __restrict__ ssq2,
                        const float* __restrict__ g2, const float* __restrict__ b2,
                        float* __restrict__ out) {
    __shared__ float ss[2];
    int o = (blockIdx.x >> 4) & 255;   // each block spans 1024 elems within one channel
    if (threadIdx.x == 0) {
        const float invn = 1.f / (float)MTOT;
        float m = sum2[o] * invn;
        float v = ssq2[o] * invn - m * m;
        float s = g2[o] * rsqrtf(v + 1e-5f);
        ss[0] = s;
        ss[1] = b2[o] - m * s;
    }
    __syncthreads();
    float s = ss[0], d = ss[1];
    size_t i = ((size_t)blockIdx.x * 256 + threadIdx.x) * 4;
    ushort4 hv = *(const ushort4*)(h2 + i);
    float4 v;
    v.x = fmaxf(bf2f(hv.x) * s + d, 0.f);
    v.y = fmaxf(bf2f(hv.y) * s + d, 0.f);
    v.z = fmaxf(bf2f(hv.z) * s + d, 0.f);
    v.w = fmaxf(bf2f(hv.w) * s + d, 0.f);
    *(float4*)&out[i] = v;
}

extern "C" void kernel_launch(void* const* d_in, const int* in_sizes, int n_in,
                              void* d_out, int out_size, void* d_ws, size_t ws_size,
                              hipStream_t stream) {
    const float* p1 = (const float*)d_in[0];
    const float* p2 = (const float*)d_in[1];
    const float* f1 = (const float*)d_in[2];
    const float* f2 = (const float*)d_in[3];
    const void*  idx = d_in[4];
    const float* W1 = (const float*)d_in[5];
    const float* g1 = (const float*)d_in[6];
    const float* b1 = (const float*)d_in[7];
    const float* W2 = (const float*)d_in[8];
    const float* g2 = (const float*)d_in[9];
    const float* b2 = (const float*)d_in[10];
    float* out = (float*)d_out;

    char* ws = (char*)d_ws;
    float* stats = (float*)(ws + STATS_OFF);
    float* sum1 = stats + 0;     float* ssq1 = stats + 256;
    float* sum2 = stats + 1024;  float* ssq2 = stats + 1280;
    int* flag64 = (int*)(ws + FLAG_OFF);
    unsigned short* W1b = (unsigned short*)(ws + W1B_OFF);
    unsigned short* W2b = (unsigned short*)(ws + W2B_OFF);
    unsigned short* f2t = (unsigned short*)(ws + F2T_OFF);
    unsigned short* xT  = (unsigned short*)(ws + XT_OFF);
    unsigned short* h2  = (unsigned short*)(ws + H2_OFF);

    unsigned short* h1 = (unsigned short*)d_out;  // 67 MB bf16 scratch in d_out

    k_prep<<<577, 256, 0, stream>>>(idx, flag64, stats, W1, W1b, W2, W2b);
    k_tr_f2<<<dim3(MM / 32, C2 / 64, BB), 256, 0, stream>>>(f2, f2t);
    k_tr_f1<<<dim3(NN / 32, 1, BB), 256, 0, stream>>>(f1, xT);
    k_interp<<<MTOT / 8, 256, 0, stream>>>(p1, p2, idx, flag64, f2t, xT);
    k_gemm1<<<dim3(MTOT / TM, CO / TN), 256, 0, stream>>>(xT, W1b, h1, sum1, ssq1);
    k_gemm2<<<dim3(MTOT / TM, CO / TN), 256, 0, stream>>>(h1, W2b, sum1, ssq1, g1, b1, h2, sum2, ssq2);
    k_apply<<<(int)((size_t)out_size / 4 / 256), 256, 0, stream>>>(h2, sum2, ssq2, g2, b2, out);
}